// Round 1
// baseline (1599.562 us; speedup 1.0000x reference)
//
#include <hip/hip_runtime.h>

// ============================================================================
// CrossAttention fused pipeline, MI355X gfx950.
// All GEMMs: bf16 MFMA 16x16x32, 128x128x32 tiles, global_load_lds staging.
// Precision-critical path (Q/K proj, QK^T) uses split-bf16 (hi+lo, 3 cross
// terms via K-concatenation) to keep attn error ~1e-5 near the alpha cliff.
// ============================================================================

typedef unsigned short u16;
typedef __attribute__((ext_vector_type(8))) short  bf16x8;   // 8 bf16 = 4 VGPRs
typedef __attribute__((ext_vector_type(4))) float  f32x4;

#define GLL16(gp, lp) __builtin_amdgcn_global_load_lds(                     \
    (__attribute__((address_space(1))) const void*)(gp),                    \
    (__attribute__((address_space(3))) void*)(lp), 16, 0, 0)

__device__ __forceinline__ u16 f2bf(float x) {
  union { float f; unsigned u; } v; v.f = x;
  return (u16)((v.u + 0x7FFF + ((v.u >> 16) & 1)) >> 16);   // RNE
}
__device__ __forceinline__ float bf2f(u16 h) {
  union { unsigned u; float f; } v; v.u = ((unsigned)h) << 16;
  return v.f;
}
__device__ __forceinline__ f32x4 zero4() { f32x4 z = {0.f, 0.f, 0.f, 0.f}; return z; }

// ---------------------------------------------------------------------------
// Pack kernels: fp32 -> bf16.  pack3: 3-way split concat along K.
//   ord 0 (A side):  [hi | lo | hi]
//   ord 1 (W side):  [hi | hi | lo]
//   dot(A', W') = hi*hi + lo*hi + hi*lo   (the 3 significant terms)
// ---------------------------------------------------------------------------
__global__ __launch_bounds__(256) void pack3(const float* __restrict__ in,
                                             u16* __restrict__ out, int ord) {
  size_t i = (size_t)blockIdx.x * 256 + threadIdx.x;
  size_t r = i >> 10, c = i & 1023;
  float x = in[i];
  u16 hi = f2bf(x);
  u16 lo = f2bf(x - bf2f(hi));
  size_t o = r * 3072 + c;
  if (ord == 0) { out[o] = hi; out[o + 1024] = lo; out[o + 2048] = hi; }
  else          { out[o] = hi; out[o + 1024] = hi; out[o + 2048] = lo; }
}

__global__ __launch_bounds__(256) void packp(const float* __restrict__ in,
                                             u16* __restrict__ out) {
  size_t i = (size_t)blockIdx.x * 256 + threadIdx.x;
  out[i] = f2bf(in[i]);
}

// ---------------------------------------------------------------------------
// GEMM: C[M,N] = A[M,K] @ W[N,K]^T   (both K-contiguous bf16, lda/ldw strides)
// Block 256 thr = 4 waves; tile 128x128, BK=32; wave -> 64x64 (4x4 MFMAs).
// Fragment layout (verified m89/m120):
//   A-frag: lane holds A[m = l&15][k = (l>>4)*8 + j]
//   B-frag: lane holds W[n = l&15][k = (l>>4)*8 + j]
//   C/D   : lane,reg r -> row m = (l>>4)*4 + r, col n = l&15
// ---------------------------------------------------------------------------
#define EPI_SPLITQ    0  // scatter hi/lo/hi -> Q2 [bh][1024][208]
#define EPI_SPLITK    1  // scatter hi/hi/lo -> K2 [bh][1024][208]
#define EPI_VT        2  // scatter bf16     -> Vt [bh][64][1024]
#define EPI_F32       3  // plain f32 row-major
#define EPI_SILU_BF16 4  // silu(v+bias) -> bf16
#define EPI_SILU_F32  5  // silu(v+bias) -> f32
#define EPI_BIAS_F32  6  // v+bias -> f32

template <int EPI>
__global__ __launch_bounds__(256) void gemm_bt(
    const u16* __restrict__ A, int lda,
    const u16* __restrict__ W, int ldw,
    int M, int N, int K,
    float* __restrict__ outF, u16* __restrict__ outU,
    const float* __restrict__ bias) {
  __shared__ u16 As[128 * 32];   // 8 KB
  __shared__ u16 Bs[128 * 32];   // 8 KB
  int tid = threadIdx.x;
  int l = tid & 63, w = tid >> 6;
  int wr = w >> 1, wc = w & 1, lr = l & 15, lq = l >> 4;
  int m0 = blockIdx.y * 128, n0 = blockIdx.x * 128;

  f32x4 acc[4][4];
#pragma unroll
  for (int i = 0; i < 4; i++)
#pragma unroll
    for (int j = 0; j < 4; j++) acc[i][j] = zero4();

  auto stage = [&](const u16* src, int ld, int r0, int k0, u16* lds) {
#pragma unroll
    for (int j = 0; j < 2; ++j) {
      int seg = w * 128 + j * 64 + l;                 // 512 x 16B segs
      const u16* g = src + (size_t)(r0 + (seg >> 2)) * ld + k0 + (seg & 3) * 8;
      GLL16(g, lds + seg * 8);
    }
  };

  int nk = K >> 5;
  stage(A, lda, m0, 0, As);
  stage(W, ldw, n0, 0, Bs);
  for (int kt = 0; kt < nk; ++kt) {
    __syncthreads();                                  // staging done (vmcnt drain)
    bf16x8 af[4], bw[4];
#pragma unroll
    for (int mi = 0; mi < 4; mi++)
      af[mi] = *(const bf16x8*)&As[(wr * 64 + mi * 16 + lr) * 32 + lq * 8];
#pragma unroll
    for (int ni = 0; ni < 4; ni++)
      bw[ni] = *(const bf16x8*)&Bs[(wc * 64 + ni * 16 + lr) * 32 + lq * 8];
#pragma unroll
    for (int mi = 0; mi < 4; mi++)
#pragma unroll
      for (int ni = 0; ni < 4; ni++)
        acc[mi][ni] = __builtin_amdgcn_mfma_f32_16x16x32_bf16(af[mi], bw[ni],
                                                              acc[mi][ni], 0, 0, 0);
    __syncthreads();                                  // reads done, safe to restage
    if (kt + 1 < nk) {
      stage(A, lda, m0, (kt + 1) << 5, As);
      stage(W, ldw, n0, (kt + 1) << 5, Bs);
    }
  }

#pragma unroll
  for (int mi = 0; mi < 4; mi++) {
#pragma unroll
    for (int ni = 0; ni < 4; ni++) {
      int col = n0 + wc * 64 + ni * 16 + lr;
#pragma unroll
      for (int r = 0; r < 4; r++) {
        int row = m0 + wr * 64 + mi * 16 + lq * 4 + r;
        float v = acc[mi][ni][r];
        if constexpr (EPI == EPI_SPLITQ || EPI == EPI_SPLITK) {
          int b = row >> 10, t = row & 1023, h = col >> 6, d = col & 63;
          size_t o = ((size_t)(b * 16 + h) * 1024 + t) * 208 + d;  // 208 = 192+16 pad (bank rotate)
          u16 hi = f2bf(v);
          u16 lo = f2bf(v - bf2f(hi));
          if constexpr (EPI == EPI_SPLITQ) { outU[o] = hi; outU[o + 64] = lo; outU[o + 128] = hi; }
          else                             { outU[o] = hi; outU[o + 64] = hi; outU[o + 128] = lo; }
        } else if constexpr (EPI == EPI_VT) {
          int b = row >> 10, t = row & 1023, h = col >> 6, d = col & 63;
          outU[((size_t)(b * 16 + h) * 64 + d) * 1024 + t] = f2bf(v);
        } else if constexpr (EPI == EPI_F32) {
          outF[(size_t)row * N + col] = v;
        } else if constexpr (EPI == EPI_SILU_BF16) {
          float z = v + bias[col];
          outU[(size_t)row * N + col] = f2bf(z / (1.f + __expf(-z)));
        } else if constexpr (EPI == EPI_SILU_F32) {
          float z = v + bias[col];
          outF[(size_t)row * N + col] = z / (1.f + __expf(-z));
        } else {  // EPI_BIAS_F32
          outF[(size_t)row * N + col] = v + bias[col];
        }
      }
    }
  }
}

// ---------------------------------------------------------------------------
// Attention: block = (qtile 16, h, b).  Q2/K2: [bh][1024][208] bf16 split-192.
// Vt: [bh][64][1024] bf16 (d-major so PV B-frags are K-contiguous).
// Scores for 16x1024 held in regs (16 f32x4/lane, MFMA C-layout).
// masked -> d_out; attn2 -> LDS (bf16, A-layout) -> PV MFMA -> attn_out.
// ---------------------------------------------------------------------------
__device__ __forceinline__ void rr_write(float v[4], float* red, int w, int lr, int lq) {
  if (lr == 0) {
#pragma unroll
    for (int r = 0; r < 4; r++) red[(lq * 4 + r) * 4 + w] = v[r];
  }
}

template <bool MAXOP>
__device__ __forceinline__ void rowreduce(float v[4], float* red, int w, int lr, int lq) {
#pragma unroll
  for (int r = 0; r < 4; r++) {
#pragma unroll
    for (int off = 1; off < 16; off <<= 1) {
      float o = __shfl_xor(v[r], off);
      v[r] = MAXOP ? fmaxf(v[r], o) : (v[r] + o);
    }
  }
  rr_write(v, red, w, lr, lq);
  __syncthreads();
#pragma unroll
  for (int r = 0; r < 4; r++) {
    int base = (lq * 4 + r) * 4;
    float a = red[base], b = red[base + 1], c = red[base + 2], d = red[base + 3];
    v[r] = MAXOP ? fmaxf(fmaxf(a, b), fmaxf(c, d)) : (a + b + c + d);
  }
  __syncthreads();
}

__global__ __launch_bounds__(256) void attn_kernel(
    const u16* __restrict__ Q2, const u16* __restrict__ K2,
    const u16* __restrict__ Vt, const float* __restrict__ alphap,
    float* __restrict__ masked_out, u16* __restrict__ attn_out) {
  __shared__ __align__(16) char smem[42496];
  u16* Qs = (u16*)smem;              // phase1: [16][208]  6656 B
  u16* Ks = (u16*)(smem + 6656);     // phase1: [64][208]  26624 B
  u16* Sb = (u16*)smem;              // phase2: [16][1032] 33024 B (aliases Qs/Ks)
  u16* Vs = (u16*)(smem + 33024);    // phase2: [64][72]   9216 B
  float* red = (float*)(smem + 42240);  // 64 f32

  int tid = threadIdx.x;
  int l = tid & 63, w = tid >> 6, lr = l & 15, lq = l >> 4;
  int q0 = blockIdx.x * 16;
  int h = blockIdx.y, b = blockIdx.z;
  int bh = b * 16 + h;
  const u16* Qb = Q2 + (size_t)bh * 1024 * 208;
  const u16* Kb = K2 + (size_t)bh * 1024 * 208;
  const u16* Vb = Vt + (size_t)bh * 64 * 1024;
  float alpha = alphap[0];

  // Q tile: 16 rows x 208 = contiguous 6656 B block in global (stride matches)
  for (int i = tid; i < 416; i += 256)
    *(uint4*)&Qs[i * 8] = *(const uint4*)(Qb + (size_t)q0 * 208 + i * 8);

  f32x4 sreg[16];  // scores: row = lq*4+r, col = kc*64 + w*16 + lr

  // ---- phase 1: S = Q K^T / 8 over split-192 ----
#pragma unroll
  for (int kc = 0; kc < 16; ++kc) {
    __syncthreads();  // prev chunk reads done (+ Qs ready at kc=0)
#pragma unroll
    for (int j = 0; j < 7; ++j) {
      int seg = j * 256 + tid;   // 1664 segs = 64 rows x 26
      if (seg < 1664) GLL16(Kb + (size_t)(kc * 64) * 208 + seg * 8, Ks + seg * 8);
    }
    __syncthreads();  // staging drained
    f32x4 acc = zero4();
#pragma unroll
    for (int kt = 0; kt < 6; ++kt) {   // 6*32 = 192 = hi|lo|hi dot hi|hi|lo
      bf16x8 af = *(const bf16x8*)&Qs[lr * 208 + kt * 32 + lq * 8];
      bf16x8 bk = *(const bf16x8*)&Ks[(w * 16 + lr) * 208 + kt * 32 + lq * 8];
      acc = __builtin_amdgcn_mfma_f32_16x16x32_bf16(af, bk, acc, 0, 0, 0);
    }
#pragma unroll
    for (int r = 0; r < 4; r++) sreg[kc][r] = acc[r] * 0.125f;  // 1/sqrt(64)
  }

  // ---- softmax 1 ----
  float m1[4];
#pragma unroll
  for (int r = 0; r < 4; r++) m1[r] = -3.0e38f;
#pragma unroll
  for (int kc = 0; kc < 16; kc++)
#pragma unroll
    for (int r = 0; r < 4; r++) m1[r] = fmaxf(m1[r], sreg[kc][r]);
  rowreduce<true>(m1, red, w, lr, lq);

  float s1[4] = {0.f, 0.f, 0.f, 0.f};
#pragma unroll
  for (int kc = 0; kc < 16; kc++)
#pragma unroll
    for (int r = 0; r < 4; r++) {
      float e = __expf(sreg[kc][r] - m1[r]);
      sreg[kc][r] = e;
      s1[r] += e;
    }
  rowreduce<false>(s1, red, w, lr, lq);

  // ---- mask + write masked + softmax 2 ----
  float m2[4];
#pragma unroll
  for (int r = 0; r < 4; r++) { s1[r] = 1.0f / s1[r]; m2[r] = 0.0f; }
  size_t mrow = (size_t)bh * 1024 + q0;
#pragma unroll
  for (int kc = 0; kc < 16; kc++)
#pragma unroll
    for (int r = 0; r < 4; r++) {
      float a = sreg[kc][r] * s1[r];
      a = (a >= alpha) ? a : 0.0f;
      sreg[kc][r] = a;
      m2[r] = fmaxf(m2[r], a);
      masked_out[(mrow + lq * 4 + r) * 1024 + kc * 64 + w * 16 + lr] = a;
    }
  rowreduce<true>(m2, red, w, lr, lq);

  float s2[4] = {0.f, 0.f, 0.f, 0.f};
#pragma unroll
  for (int kc = 0; kc < 16; kc++)
#pragma unroll
    for (int r = 0; r < 4; r++) {
      float e = __expf(sreg[kc][r] - m2[r]);  // zeros -> exp(-m2), all 1024 cols count
      sreg[kc][r] = e;
      s2[r] += e;
    }
  rowreduce<false>(s2, red, w, lr, lq);
#pragma unroll
  for (int r = 0; r < 4; r++) s2[r] = 1.0f / s2[r];

  // attn2 -> Sb (bf16, A-operand layout rows=q)
#pragma unroll
  for (int kc = 0; kc < 16; kc++)
#pragma unroll
    for (int r = 0; r < 4; r++)
      Sb[(lq * 4 + r) * 1032 + kc * 64 + w * 16 + lr] = f2bf(sreg[kc][r] * s2[r]);

  // ---- phase 2: O = attn2 @ V  (B-frags from Vt rows = d) ----
  f32x4 oacc = zero4();
  for (int tc = 0; tc < 16; ++tc) {
    __syncthreads();  // Sb visible (tc=0) / Vs reuse safe
#pragma unroll
    for (int j = 0; j < 2; ++j) {
      int seg = j * 256 + tid;  // 512 segs = 64 rows x 8
      int row = seg >> 3, part = seg & 7;
      *(uint4*)&Vs[row * 72 + part * 8] =
          *(const uint4*)(Vb + (size_t)row * 1024 + tc * 64 + part * 8);
    }
    __syncthreads();
#pragma unroll
    for (int kt = 0; kt < 2; ++kt) {
      bf16x8 af = *(const bf16x8*)&Sb[lr * 1032 + tc * 64 + kt * 32 + lq * 8];
      bf16x8 bv = *(const bf16x8*)&Vs[(w * 16 + lr) * 72 + kt * 32 + lq * 8];
      oacc = __builtin_amdgcn_mfma_f32_16x16x32_bf16(af, bv, oacc, 0, 0, 0);
    }
  }
#pragma unroll
  for (int r = 0; r < 4; r++) {
    int q = q0 + lq * 4 + r;
    attn_out[(size_t)(b * 1024 + q) * 1024 + h * 64 + w * 16 + lr] = f2bf(oacc[r]);
  }
}

// ---------------------------------------------------------------------------
// LayerNorm over D=1024: y = (a+b - mu)*rsqrt(var+eps)*g + beta
// ---------------------------------------------------------------------------
__global__ __launch_bounds__(256) void ln_kernel(
    const float* __restrict__ A, const float* __restrict__ Bv,
    const float* __restrict__ g, const float* __restrict__ beta,
    float* __restrict__ outF, u16* __restrict__ outB) {
  __shared__ float red[4];
  int row = blockIdx.x, t = threadIdx.x;
  const float* pa = A + (size_t)row * 1024;
  const float* pb = Bv + (size_t)row * 1024;
  float v[4];
  float s = 0.f;
#pragma unroll
  for (int i = 0; i < 4; i++) { int c = t + 256 * i; v[i] = pa[c] + pb[c]; s += v[i]; }
#pragma unroll
  for (int off = 1; off < 64; off <<= 1) s += __shfl_xor(s, off);
  if ((t & 63) == 0) red[t >> 6] = s;
  __syncthreads();
  s = red[0] + red[1] + red[2] + red[3];
  float mu = s * 0.0009765625f;
  float q = 0.f;
#pragma unroll
  for (int i = 0; i < 4; i++) { float d = v[i] - mu; q += d * d; }
  __syncthreads();
#pragma unroll
  for (int off = 1; off < 64; off <<= 1) q += __shfl_xor(q, off);
  if ((t & 63) == 0) red[t >> 6] = q;
  __syncthreads();
  q = red[0] + red[1] + red[2] + red[3];
  float rs = rsqrtf(q * 0.0009765625f + 1e-5f);
#pragma unroll
  for (int i = 0; i < 4; i++) {
    int c = t + 256 * i;
    float y = (v[i] - mu) * rs * g[c] + beta[c];
    if (outF) outF[(size_t)row * 1024 + c] = y;
    if (outB) outB[(size_t)row * 1024 + c] = f2bf(y);
  }
}

// ---------------------------------------------------------------------------
// Workspace layout (bytes). Aliased by lifetime; total 266,338,304 B.
// ---------------------------------------------------------------------------
#define WS_BASE3   0            // [8192][3072] u16  = 50331648   (dead after Q gemm)
#define WS_FUSION3 50331648     // [8192][3072] u16  = 50331648   (dead after K,V gemms)
#define WS_WQ3     100663296    // [1024][3072] u16  = 6291456
#define WS_WK3     106954752    // 6291456
#define WS_WV      113246208    // [1024][1024] u16  = 2097152
#define WS_WO      115343360
#define WS_WFC1    117440512
#define WS_WFC2    119537664
#define WS_WRW     121634816
#define WS_Q2      123731968    // [128][1024][208] u16 = 54525952 (dead after attn)
#define WS_K2      178257920    // 54525952                        (dead after attn)
#define WS_VT      232783872    // [128][64][1024] u16 = 16777216
#define WS_ATTNO   249561088    // [8192][1024] u16 = 16777216
#define WS_O       WS_BASE3                  // [8192][1024] f32 (alias base3)
#define WS_X       WS_FUSION3                // [8192][1024] f32 (alias fusion3)
#define WS_XB      (WS_FUSION3 + 33554432)   // [8192][1024] u16
#define WS_H1      WS_Q2                     // [8192][1024] u16 (alias Q2)
#define WS_FF      (WS_Q2 + 16777216)        // [8192][1024] f32
#define WS_YB      WS_K2                     // [8192][1024] u16 (alias K2)

extern "C" void kernel_launch(void* const* d_in, const int* in_sizes, int n_in,
                              void* d_out, int out_size, void* d_ws, size_t ws_size,
                              hipStream_t stream) {
  const float* base   = (const float*)d_in[0];
  const float* fusion = (const float*)d_in[1];
  const float* Wq     = (const float*)d_in[2];
  const float* Wk     = (const float*)d_in[3];
  const float* Wv     = (const float*)d_in[4];
  const float* Wo     = (const float*)d_in[5];
  const float* g1     = (const float*)d_in[6];
  const float* b1     = (const float*)d_in[7];
  const float* g2     = (const float*)d_in[8];
  const float* b2     = (const float*)d_in[9];
  const float* fc1w   = (const float*)d_in[10];
  const float* fc1b   = (const float*)d_in[11];
  const float* fc2w   = (const float*)d_in[12];
  const float* fc2b   = (const float*)d_in[13];
  const float* rw     = (const float*)d_in[14];
  const float* rb     = (const float*)d_in[15];
  const float* alphap = (const float*)d_in[16];

  char* ws = (char*)d_ws;
  u16* base3   = (u16*)(ws + WS_BASE3);
  u16* fusion3 = (u16*)(ws + WS_FUSION3);
  u16* wq3     = (u16*)(ws + WS_WQ3);
  u16* wk3     = (u16*)(ws + WS_WK3);
  u16* wv      = (u16*)(ws + WS_WV);
  u16* wo      = (u16*)(ws + WS_WO);
  u16* wfc1    = (u16*)(ws + WS_WFC1);
  u16* wfc2    = (u16*)(ws + WS_WFC2);
  u16* wrw     = (u16*)(ws + WS_WRW);
  u16* Q2      = (u16*)(ws + WS_Q2);
  u16* K2      = (u16*)(ws + WS_K2);
  u16* Vt      = (u16*)(ws + WS_VT);
  u16* attno   = (u16*)(ws + WS_ATTNO);
  float* obuf  = (float*)(ws + WS_O);
  float* x     = (float*)(ws + WS_X);
  u16* xb      = (u16*)(ws + WS_XB);
  u16* h1      = (u16*)(ws + WS_H1);
  float* ff    = (float*)(ws + WS_FF);
  u16* yb      = (u16*)(ws + WS_YB);

  float* final_out  = (float*)d_out;                // [8][1024][1024]
  float* masked_out = final_out + 8388608;          // [8][16][1024][1024]

  // 1. pack fp32 -> bf16 (split for precision-critical Q/K path)
  pack3<<<32768, 256, 0, stream>>>(base, base3, 0);
  pack3<<<32768, 256, 0, stream>>>(fusion, fusion3, 0);
  pack3<<<4096, 256, 0, stream>>>(Wq, wq3, 1);
  pack3<<<4096, 256, 0, stream>>>(Wk, wk3, 1);
  packp<<<4096, 256, 0, stream>>>(Wv, wv);
  packp<<<4096, 256, 0, stream>>>(Wo, wo);
  packp<<<4096, 256, 0, stream>>>(fc1w, wfc1);
  packp<<<4096, 256, 0, stream>>>(fc2w, wfc2);
  packp<<<4096, 256, 0, stream>>>(rw, wrw);

  dim3 gg(8, 64);  // N/128, M/128

  // 2. projections (Q/K split-K=3072, epilogue scatters into attention layouts)
  gemm_bt<EPI_SPLITQ><<<gg, 256, 0, stream>>>(base3, 3072, wq3, 3072, 8192, 1024, 3072,
                                              nullptr, Q2, nullptr);
  gemm_bt<EPI_SPLITK><<<gg, 256, 0, stream>>>(fusion3, 3072, wk3, 3072, 8192, 1024, 3072,
                                              nullptr, K2, nullptr);
  gemm_bt<EPI_VT><<<gg, 256, 0, stream>>>(fusion3, 3072, wv, 1024, 8192, 1024, 1024,
                                          nullptr, Vt, nullptr);

  // 3. attention (masked -> d_out, O -> attno)
  attn_kernel<<<dim3(64, 16, 8), 256, 0, stream>>>(Q2, K2, Vt, alphap, masked_out, attno);

  // 4. output proj + LN1
  gemm_bt<EPI_F32><<<gg, 256, 0, stream>>>(attno, 1024, wo, 1024, 8192, 1024, 1024,
                                           obuf, nullptr, nullptr);
  ln_kernel<<<8192, 256, 0, stream>>>(base, obuf, g1, b1, x, xb);

  // 5. FFN + LN2
  gemm_bt<EPI_SILU_BF16><<<gg, 256, 0, stream>>>(xb, 1024, wfc1, 1024, 8192, 1024, 1024,
                                                 nullptr, h1, fc1b);
  gemm_bt<EPI_SILU_F32><<<gg, 256, 0, stream>>>(h1, 1024, wfc2, 1024, 8192, 1024, 1024,
                                                ff, nullptr, fc2b);
  ln_kernel<<<8192, 256, 0, stream>>>(x, ff, g2, b2, nullptr, yb);

  // 6. final projection
  gemm_bt<EPI_BIAS_F32><<<gg, 256, 0, stream>>>(yb, 1024, wrw, 1024, 8192, 1024, 1024,
                                                final_out, nullptr, rb);
}

// Round 2
// 1238.980 us; speedup vs baseline: 1.2910x; 1.2910x over previous
//
#include <hip/hip_runtime.h>

// ============================================================================
// CrossAttention fused pipeline, MI355X gfx950.  Round 2.
// Attention: two-pass recompute, 128 q-rows/block, swizzled K2/Vt layouts.
// ============================================================================

typedef unsigned short u16;
typedef __attribute__((ext_vector_type(8))) short  bf16x8;
typedef __attribute__((ext_vector_type(4))) float  f32x4;

#define GLL16(gp, lp) __builtin_amdgcn_global_load_lds(                     \
    (__attribute__((address_space(1))) const void*)(gp),                    \
    (__attribute__((address_space(3))) void*)(lp), 16, 0, 0)

__device__ __forceinline__ u16 f2bf(float x) {
  union { float f; unsigned u; } v; v.f = x;
  return (u16)((v.u + 0x7FFF + ((v.u >> 16) & 1)) >> 16);
}
__device__ __forceinline__ float bf2f(u16 h) {
  union { unsigned u; float f; } v; v.u = ((unsigned)h) << 16;
  return v.f;
}
__device__ __forceinline__ f32x4 zero4() { f32x4 z = {0.f, 0.f, 0.f, 0.f}; return z; }

__global__ __launch_bounds__(256) void pack3(const float* __restrict__ in,
                                             u16* __restrict__ out, int ord) {
  size_t i = (size_t)blockIdx.x * 256 + threadIdx.x;
  size_t r = i >> 10, c = i & 1023;
  float x = in[i];
  u16 hi = f2bf(x);
  u16 lo = f2bf(x - bf2f(hi));
  size_t o = r * 3072 + c;
  if (ord == 0) { out[o] = hi; out[o + 1024] = lo; out[o + 2048] = hi; }
  else          { out[o] = hi; out[o + 1024] = hi; out[o + 2048] = lo; }
}

__global__ __launch_bounds__(256) void packp(const float* __restrict__ in,
                                             u16* __restrict__ out) {
  size_t i = (size_t)blockIdx.x * 256 + threadIdx.x;
  out[i] = f2bf(in[i]);
}

#define EPI_VT        2
#define EPI_F32       3
#define EPI_SILU_BF16 4
#define EPI_SILU_F32  5
#define EPI_BIAS_F32  6
#define EPI_QK        7

template <int EPI>
__global__ __launch_bounds__(256) void gemm_bt(
    const u16* __restrict__ A, int lda,
    const u16* __restrict__ W, int ldw,
    int M, int N, int K,
    float* __restrict__ outF, u16* __restrict__ outU,
    const float* __restrict__ bias,
    const u16* __restrict__ A2, const u16* __restrict__ W2) {
  __shared__ u16 As[128 * 32];
  __shared__ u16 Bs[128 * 32];
  int tid = threadIdx.x;
  int l = tid & 63, w = tid >> 6;
  int wr = w >> 1, wc = w & 1, lr = l & 15, lq = l >> 4;
  int m0 = blockIdx.y * 128, n0 = blockIdx.x * 128;

  const u16* Ap = A;
  const u16* Wp = W;
  u16* outUp = outU;
  if constexpr (EPI == EPI_QK) {
    if (blockIdx.z == 1) { Ap = A2; Wp = W2; outUp = outU + 16777216; }  // K2
  }

  f32x4 acc[4][4];
#pragma unroll
  for (int i = 0; i < 4; i++)
#pragma unroll
    for (int j = 0; j < 4; j++) acc[i][j] = zero4();

  auto stage = [&](const u16* src, int ld, int r0, int k0, u16* lds) {
#pragma unroll
    for (int j = 0; j < 2; ++j) {
      int seg = w * 128 + j * 64 + l;
      const u16* g = src + (size_t)(r0 + (seg >> 2)) * ld + k0 + (seg & 3) * 8;
      GLL16(g, lds + seg * 8);
    }
  };

  int nk = K >> 5;
  stage(Ap, lda, m0, 0, As);
  stage(Wp, ldw, n0, 0, Bs);
  for (int kt = 0; kt < nk; ++kt) {
    __syncthreads();
    bf16x8 af[4], bw[4];
#pragma unroll
    for (int mi = 0; mi < 4; mi++)
      af[mi] = *(const bf16x8*)&As[(wr * 64 + mi * 16 + lr) * 32 + lq * 8];
#pragma unroll
    for (int ni = 0; ni < 4; ni++)
      bw[ni] = *(const bf16x8*)&Bs[(wc * 64 + ni * 16 + lr) * 32 + lq * 8];
#pragma unroll
    for (int mi = 0; mi < 4; mi++)
#pragma unroll
      for (int ni = 0; ni < 4; ni++)
        acc[mi][ni] = __builtin_amdgcn_mfma_f32_16x16x32_bf16(af[mi], bw[ni],
                                                              acc[mi][ni], 0, 0, 0);
    __syncthreads();
    if (kt + 1 < nk) {
      stage(Ap, lda, m0, (kt + 1) << 5, As);
      stage(Wp, ldw, n0, (kt + 1) << 5, Bs);
    }
  }

#pragma unroll
  for (int mi = 0; mi < 4; mi++) {
#pragma unroll
    for (int ni = 0; ni < 4; ni++) {
      int col = n0 + wc * 64 + ni * 16 + lr;
#pragma unroll
      for (int r = 0; r < 4; r++) {
        int row = m0 + wr * 64 + mi * 16 + lq * 4 + r;
        float v = acc[mi][ni][r];
        if constexpr (EPI == EPI_QK) {
          int b = row >> 10, t = row & 1023, h = col >> 6, d = col & 63;
          size_t base = ((size_t)(b * 16 + h) * 1024 + t) * 128;
          u16 hi = f2bf(v);
          u16 lo = f2bf(v - bf2f(hi));
          if (blockIdx.z == 0) {
            outUp[base + d] = hi;
            outUp[base + 64 + d] = lo;
          } else {
            int sh = ((d >> 3) ^ (t & 15));
            int sl = ((8 + (d >> 3)) ^ (t & 15));
            outUp[base + (sh << 3) + (d & 7)] = hi;
            outUp[base + (sl << 3) + (d & 7)] = lo;
          }
        } else if constexpr (EPI == EPI_VT) {
          int b = row >> 10, t = row & 1023, h = col >> 6, d = col & 63;
          size_t o = ((size_t)(b * 16 + h) * 64 + d) * 1024 + (t & ~63) +
                     (((((t >> 3) & 7) ^ (d & 7))) << 3) + (t & 7);
          outUp[o] = f2bf(v);
        } else if constexpr (EPI == EPI_F32) {
          outF[(size_t)row * N + col] = v;
        } else if constexpr (EPI == EPI_SILU_BF16) {
          float z = v + bias[col];
          outUp[(size_t)row * N + col] = f2bf(z / (1.f + __expf(-z)));
        } else if constexpr (EPI == EPI_SILU_F32) {
          float z = v + bias[col];
          outF[(size_t)row * N + col] = z / (1.f + __expf(-z));
        } else {
          outF[(size_t)row * N + col] = v + bias[col];
        }
      }
    }
  }
}

__global__ __launch_bounds__(256) void attn_kernel(
    const u16* __restrict__ Q2, const u16* __restrict__ K2,
    const u16* __restrict__ Vt, const float* __restrict__ alphap,
    float* __restrict__ masked_out, u16* __restrict__ attn_out) {
  __shared__ __align__(16) u16 Ks[8192];
  __shared__ __align__(16) u16 Vs[4096];
  __shared__ __align__(16) u16 Ps[4][2][16 * 72];

  int tid = threadIdx.x;
  int l = tid & 63, w = tid >> 6, lr = l & 15, lq = l >> 4;
  int q0 = blockIdx.x * 128;
  int h = blockIdx.y, b = blockIdx.z;
  int bh = b * 16 + h;
  const u16* Qb = Q2 + (size_t)bh * 1024 * 128;
  const u16* Kb = K2 + (size_t)bh * 1024 * 128;
  const u16* Vb = Vt + (size_t)bh * 64 * 1024;
  float alpha = alphap[0];
  int qw = q0 + w * 32;

  bf16x8 qf[2][4];
#pragma unroll
  for (int s = 0; s < 2; s++)
#pragma unroll
    for (int f = 0; f < 4; f++)
      qf[s][f] = *(const bf16x8*)(Qb + (size_t)(qw + s * 16 + lr) * 128 + f * 32 + lq * 8);

  float s1[2][4] = {{0.f, 0.f, 0.f, 0.f}, {0.f, 0.f, 0.f, 0.f}};

  for (int kc = 0; kc < 16; ++kc) {
    __syncthreads();
#pragma unroll
    for (int j = 0; j < 4; ++j) {
      int seg = j * 256 + tid;
      GLL16(Kb + (size_t)kc * 8192 + seg * 8, Ks + seg * 8);
    }
    __syncthreads();
    f32x4 acc[2][4];
#pragma unroll
    for (int s = 0; s < 2; s++)
#pragma unroll
      for (int ni = 0; ni < 4; ni++) acc[s][ni] = zero4();
#pragma unroll
    for (int ni = 0; ni < 4; ++ni) {
      int t = ni * 16 + lr;
      bf16x8 kh0 = *(const bf16x8*)&Ks[t * 128 + (((0 + lq) ^ lr) << 3)];
      bf16x8 kh1 = *(const bf16x8*)&Ks[t * 128 + (((4 + lq) ^ lr) << 3)];
      bf16x8 kl0 = *(const bf16x8*)&Ks[t * 128 + (((8 + lq) ^ lr) << 3)];
      bf16x8 kl1 = *(const bf16x8*)&Ks[t * 128 + (((12 + lq) ^ lr) << 3)];
#pragma unroll
      for (int s = 0; s < 2; s++) {
        f32x4 a = acc[s][ni];
        a = __builtin_amdgcn_mfma_f32_16x16x32_bf16(qf[s][0], kh0, a, 0, 0, 0);
        a = __builtin_amdgcn_mfma_f32_16x16x32_bf16(qf[s][1], kh1, a, 0, 0, 0);
        a = __builtin_amdgcn_mfma_f32_16x16x32_bf16(qf[s][0], kl0, a, 0, 0, 0);
        a = __builtin_amdgcn_mfma_f32_16x16x32_bf16(qf[s][1], kl1, a, 0, 0, 0);
        a = __builtin_amdgcn_mfma_f32_16x16x32_bf16(qf[s][2], kh0, a, 0, 0, 0);
        a = __builtin_amdgcn_mfma_f32_16x16x32_bf16(qf[s][3], kh1, a, 0, 0, 0);
        acc[s][ni] = a;
      }
    }
#pragma unroll
    for (int s = 0; s < 2; s++)
#pragma unroll
      for (int ni = 0; ni < 4; ni++)
#pragma unroll
        for (int r = 0; r < 4; r++)
          s1[s][r] += __expf(acc[s][ni][r] * 0.125f);
  }
#pragma unroll
  for (int s = 0; s < 2; s++)
#pragma unroll
    for (int r = 0; r < 4; r++) {
      float v = s1[s][r];
      v += __shfl_xor(v, 1); v += __shfl_xor(v, 2);
      v += __shfl_xor(v, 4); v += __shfl_xor(v, 8);
      s1[s][r] = 1.0f / v;
    }

  float s2[2][4] = {{0.f, 0.f, 0.f, 0.f}, {0.f, 0.f, 0.f, 0.f}};
  f32x4 oacc[2][4];
#pragma unroll
  for (int s = 0; s < 2; s++)
#pragma unroll
    for (int dg = 0; dg < 4; dg++) oacc[s][dg] = zero4();

  for (int kc = 0; kc < 16; ++kc) {
    __syncthreads();
#pragma unroll
    for (int j = 0; j < 4; ++j) {
      int seg = j * 256 + tid;
      GLL16(Kb + (size_t)kc * 8192 + seg * 8, Ks + seg * 8);
    }
#pragma unroll
    for (int j = 0; j < 2; ++j) {
      int seg = j * 256 + tid;
      GLL16(Vb + (size_t)(seg >> 3) * 1024 + kc * 64 + (seg & 7) * 8, Vs + seg * 8);
    }
    __syncthreads();

    f32x4 acc[2][4];
#pragma unroll
    for (int s = 0; s < 2; s++)
#pragma unroll
      for (int ni = 0; ni < 4; ni++) acc[s][ni] = zero4();
#pragma unroll
    for (int ni = 0; ni < 4; ++ni) {
      int t = ni * 16 + lr;
      bf16x8 kh0 = *(const bf16x8*)&Ks[t * 128 + (((0 + lq) ^ lr) << 3)];
      bf16x8 kh1 = *(const bf16x8*)&Ks[t * 128 + (((4 + lq) ^ lr) << 3)];
      bf16x8 kl0 = *(const bf16x8*)&Ks[t * 128 + (((8 + lq) ^ lr) << 3)];
      bf16x8 kl1 = *(const bf16x8*)&Ks[t * 128 + (((12 + lq) ^ lr) << 3)];
#pragma unroll
      for (int s = 0; s < 2; s++) {
        f32x4 a = acc[s][ni];
        a = __builtin_amdgcn_mfma_f32_16x16x32_bf16(qf[s][0], kh0, a, 0, 0, 0);
        a = __builtin_amdgcn_mfma_f32_16x16x32_bf16(qf[s][1], kh1, a, 0, 0, 0);
        a = __builtin_amdgcn_mfma_f32_16x16x32_bf16(qf[s][0], kl0, a, 0, 0, 0);
        a = __builtin_amdgcn_mfma_f32_16x16x32_bf16(qf[s][1], kl1, a, 0, 0, 0);
        a = __builtin_amdgcn_mfma_f32_16x16x32_bf16(qf[s][2], kh0, a, 0, 0, 0);
        a = __builtin_amdgcn_mfma_f32_16x16x32_bf16(qf[s][3], kh1, a, 0, 0, 0);
        acc[s][ni] = a;
      }
    }

#pragma unroll
    for (int s = 0; s < 2; s++) {
#pragma unroll
      for (int ni = 0; ni < 4; ni++) {
#pragma unroll
        for (int r = 0; r < 4; r++) {
          float e = __expf(acc[s][ni][r] * 0.125f);
          float a = e * s1[s][r];
          a = (a >= alpha) ? a : 0.0f;
          size_t row = (size_t)bh * 1024 + qw + s * 16 + lq * 4 + r;
          masked_out[row * 1024 + kc * 64 + ni * 16 + lr] = a;
          float p = __expf(a);
          s2[s][r] += p;
          Ps[w][s][(lq * 4 + r) * 72 + ni * 16 + lr] = f2bf(p);
        }
      }
    }
    asm volatile("s_waitcnt lgkmcnt(0)" ::: "memory");

    bf16x8 pf[2][2];
#pragma unroll
    for (int s = 0; s < 2; s++)
#pragma unroll
      for (int kt = 0; kt < 2; kt++)
        pf[s][kt] = *(const bf16x8*)&Ps[w][s][lr * 72 + kt * 32 + lq * 8];
#pragma unroll
    for (int dg = 0; dg < 4; dg++) {
      int d = dg * 16 + lr;
      bf16x8 v0 = *(const bf16x8*)&Vs[d * 64 + (((0 + lq) ^ (lr & 7)) << 3)];
      bf16x8 v1 = *(const bf16x8*)&Vs[d * 64 + (((4 + lq) ^ (lr & 7)) << 3)];
#pragma unroll
      for (int s = 0; s < 2; s++) {
        oacc[s][dg] = __builtin_amdgcn_mfma_f32_16x16x32_bf16(pf[s][0], v0, oacc[s][dg], 0, 0, 0);
        oacc[s][dg] = __builtin_amdgcn_mfma_f32_16x16x32_bf16(pf[s][1], v1, oacc[s][dg], 0, 0, 0);
      }
    }
  }

#pragma unroll
  for (int s = 0; s < 2; s++)
#pragma unroll
    for (int r = 0; r < 4; r++) {
      float v = s2[s][r];
      v += __shfl_xor(v, 1); v += __shfl_xor(v, 2);
      v += __shfl_xor(v, 4); v += __shfl_xor(v, 8);
      s2[s][r] = 1.0f / v;
    }
#pragma unroll
  for (int s = 0; s < 2; s++)
#pragma unroll
    for (int dg = 0; dg < 4; dg++)
#pragma unroll
      for (int r = 0; r < 4; r++) {
        int q = qw + s * 16 + lq * 4 + r;
        attn_out[(size_t)(b * 1024 + q) * 1024 + h * 64 + dg * 16 + lr] =
            f2bf(oacc[s][dg][r] * s2[s][r]);
      }
}

__global__ __launch_bounds__(256) void ln_kernel(
    const float* __restrict__ A, const float* __restrict__ Bv,
    const float* __restrict__ g, const float* __restrict__ beta,
    float* __restrict__ outF, u16* __restrict__ outB) {
  __shared__ float red[4];
  int row = blockIdx.x, t = threadIdx.x;
  const float* pa = A + (size_t)row * 1024;
  const float* pb = Bv + (size_t)row * 1024;
  float v[4];
  float s = 0.f;
#pragma unroll
  for (int i = 0; i < 4; i++) { int c = t + 256 * i; v[i] = pa[c] + pb[c]; s += v[i]; }
#pragma unroll
  for (int off = 1; off < 64; off <<= 1) s += __shfl_xor(s, off);
  if ((t & 63) == 0) red[t >> 6] = s;
  __syncthreads();
  s = red[0] + red[1] + red[2] + red[3];
  float mu = s * 0.0009765625f;
  float q = 0.f;
#pragma unroll
  for (int i = 0; i < 4; i++) { float d = v[i] - mu; q += d * d; }
  __syncthreads();
#pragma unroll
  for (int off = 1; off < 64; off <<= 1) q += __shfl_xor(q, off);
  if ((t & 63) == 0) red[t >> 6] = q;
  __syncthreads();
  q = red[0] + red[1] + red[2] + red[3];
  float rs = rsqrtf(q * 0.0009765625f + 1e-5f);
#pragma unroll
  for (int i = 0; i < 4; i++) {
    int c = t + 256 * i;
    float y = (v[i] - mu) * rs * g[c] + beta[c];
    if (outF) outF[(size_t)row * 1024 + c] = y;
    if (outB) outB[(size_t)row * 1024 + c] = f2bf(y);
  }
}

#define WS_BASE3   0
#define WS_FUSION3 50331648
#define WS_WQ3     100663296
#define WS_WK3     106954752
#define WS_WV      113246208
#define WS_WO      115343360
#define WS_WFC1    117440512
#define WS_WFC2    119537664
#define WS_WRW     121634816
#define WS_Q2      123731968
#define WS_K2      157286400
#define WS_VT      190840832
#define WS_ATTNO   207618048
#define WS_O       WS_BASE3
#define WS_X       WS_FUSION3
#define WS_XB      (WS_FUSION3 + 33554432)
#define WS_H1      WS_Q2
#define WS_YB      (WS_Q2 + 16777216)
#define WS_FF      WS_K2

extern "C" void kernel_launch(void* const* d_in, const int* in_sizes, int n_in,
                              void* d_out, int out_size, void* d_ws, size_t ws_size,
                              hipStream_t stream) {
  const float* base   = (const float*)d_in[0];
  const float* fusion = (const float*)d_in[1];
  const float* Wq     = (const float*)d_in[2];
  const float* Wk     = (const float*)d_in[3];
  const float* Wv     = (const float*)d_in[4];
  const float* Wo     = (const float*)d_in[5];
  const float* g1     = (const float*)d_in[6];
  const float* b1     = (const float*)d_in[7];
  const float* g2     = (const float*)d_in[8];
  const float* b2     = (const float*)d_in[9];
  const float* fc1w   = (const float*)d_in[10];
  const float* fc1b   = (const float*)d_in[11];
  const float* fc2w   = (const float*)d_in[12];
  const float* fc2b   = (const float*)d_in[13];
  const float* rw     = (const float*)d_in[14];
  const float* rb     = (const float*)d_in[15];
  const float* alphap = (const float*)d_in[16];

  char* ws = (char*)d_ws;
  u16* base3   = (u16*)(ws + WS_BASE3);
  u16* fusion3 = (u16*)(ws + WS_FUSION3);
  u16* wq3     = (u16*)(ws + WS_WQ3);
  u16* wk3     = (u16*)(ws + WS_WK3);
  u16* wv      = (u16*)(ws + WS_WV);
  u16* wo      = (u16*)(ws + WS_WO);
  u16* wfc1    = (u16*)(ws + WS_WFC1);
  u16* wfc2    = (u16*)(ws + WS_WFC2);
  u16* wrw     = (u16*)(ws + WS_WRW);
  u16* Q2      = (u16*)(ws + WS_Q2);
  u16* K2      = (u16*)(ws + WS_K2);
  u16* Vt      = (u16*)(ws + WS_VT);
  u16* attno   = (u16*)(ws + WS_ATTNO);
  float* obuf  = (float*)(ws + WS_O);
  float* x     = (float*)(ws + WS_X);
  u16* xb      = (u16*)(ws + WS_XB);
  u16* h1      = (u16*)(ws + WS_H1);
  float* ff    = (float*)(ws + WS_FF);
  u16* yb      = (u16*)(ws + WS_YB);

  float* final_out  = (float*)d_out;
  float* masked_out = final_out + 8388608;

  pack3<<<32768, 256, 0, stream>>>(base, base3, 0);
  pack3<<<32768, 256, 0, stream>>>(fusion, fusion3, 0);
  pack3<<<4096, 256, 0, stream>>>(Wq, wq3, 1);
  pack3<<<4096, 256, 0, stream>>>(Wk, wk3, 1);
  packp<<<4096, 256, 0, stream>>>(Wv, wv);
  packp<<<4096, 256, 0, stream>>>(Wo, wo);
  packp<<<4096, 256, 0, stream>>>(fc1w, wfc1);
  packp<<<4096, 256, 0, stream>>>(fc2w, wfc2);
  packp<<<4096, 256, 0, stream>>>(rw, wrw);

  dim3 gg(8, 64);

  // Q+K merged: z=0 -> Q2 (outU), z=1 -> K2 (outU + 16777216 elements)
  gemm_bt<EPI_QK><<<dim3(8, 64, 2), 256, 0, stream>>>(
      base3, 3072, wq3, 3072, 8192, 1024, 3072, nullptr, Q2, nullptr,
      fusion3, wk3);
  gemm_bt<EPI_VT><<<gg, 256, 0, stream>>>(fusion3, 3072, wv, 1024, 8192, 1024, 1024,
                                          nullptr, Vt, nullptr, nullptr, nullptr);

  attn_kernel<<<dim3(8, 16, 8), 256, 0, stream>>>(Q2, K2, Vt, alphap,
                                                  masked_out, attno);

  gemm_bt<EPI_F32><<<gg, 256, 0, stream>>>(attno, 1024, wo, 1024, 8192, 1024, 1024,
                                           obuf, nullptr, nullptr, nullptr, nullptr);
  ln_kernel<<<8192, 256, 0, stream>>>(base, obuf, g1, b1, x, xb);

  gemm_bt<EPI_SILU_BF16><<<gg, 256, 0, stream>>>(xb, 1024, wfc1, 1024, 8192, 1024, 1024,
                                                 nullptr, h1, fc1b, nullptr, nullptr);
  gemm_bt<EPI_SILU_F32><<<gg, 256, 0, stream>>>(h1, 1024, wfc2, 1024, 8192, 1024, 1024,
                                                ff, nullptr, fc2b, nullptr, nullptr);
  ln_kernel<<<8192, 256, 0, stream>>>(x, ff, g2, b2, nullptr, yb);

  gemm_bt<EPI_BIAS_F32><<<gg, 256, 0, stream>>>(yb, 1024, wrw, 1024, 8192, 1024, 1024,
                                                final_out, nullptr, rb, nullptr, nullptr);
}

// Round 4
// 1054.200 us; speedup vs baseline: 1.5173x; 1.1753x over previous
//
#include <hip/hip_runtime.h>

// ============================================================================
// CrossAttention fused pipeline, MI355X gfx950.  Round 4.
// - GEMM: round-2-proven BK=32 double-barrier K-loop (m97 sync structure),
//   plus deterministic XOR-((row>>1)&3) LDS swizzle -> <=2-way (free) LDS reads.
// - Attention: two-pass recompute, plain bf16, Ps handoff via __syncthreads
//   (no inline-asm waitcnt, no same-wave DS-ordering assumption).
// - Merged QKV / merged packs / swizzled K2/Vt global layouts kept.
// ============================================================================

typedef unsigned short u16;
typedef __attribute__((ext_vector_type(8))) short  bf16x8;
typedef __attribute__((ext_vector_type(4))) float  f32x4;

#define GLL16(gp, lp) __builtin_amdgcn_global_load_lds(                     \
    (__attribute__((address_space(1))) const void*)(gp),                    \
    (__attribute__((address_space(3))) void*)(lp), 16, 0, 0)

__device__ __forceinline__ u16 f2bf(float x) {
  union { float f; unsigned u; } v; v.f = x;
  return (u16)((v.u + 0x7FFF + ((v.u >> 16) & 1)) >> 16);   // RNE
}
__device__ __forceinline__ f32x4 zero4() { f32x4 z = {0.f, 0.f, 0.f, 0.f}; return z; }

// ---------------------------------------------------------------------------
// Packing: activations (base,fusion) and 7 weights, fp32 -> bf16.
// ---------------------------------------------------------------------------
__global__ __launch_bounds__(256) void pack_act(const float* __restrict__ a,
                                                const float* __restrict__ b,
                                                u16* __restrict__ outa,
                                                u16* __restrict__ outb) {
  size_t i = (size_t)blockIdx.x * 256 + threadIdx.x;
  const float* in = blockIdx.y ? b : a;
  u16* out = blockIdx.y ? outb : outa;
  out[i] = f2bf(in[i]);
}

__global__ __launch_bounds__(256) void pack_w(
    const float* __restrict__ w0, const float* __restrict__ w1,
    const float* __restrict__ w2, const float* __restrict__ w3,
    const float* __restrict__ w4, const float* __restrict__ w5,
    const float* __restrict__ w6, u16* __restrict__ out) {
  size_t i = (size_t)blockIdx.x * 256 + threadIdx.x;
  const float* in;
  switch (blockIdx.y) {
    case 0: in = w0; break;  case 1: in = w1; break;
    case 2: in = w2; break;  case 3: in = w3; break;
    case 4: in = w4; break;  case 5: in = w5; break;
    default: in = w6; break;
  }
  out[(size_t)blockIdx.y * 1048576 + i] = f2bf(in[i]);
}

// ---------------------------------------------------------------------------
// GEMM: C[M,N] = A[M,K] @ W[N,K]^T, bf16, BK=32 (m97-proven sync structure).
// LDS tile 128x32 (8 KB): row r holds 4x16B blocks; global block g stored at
// slot g ^ ((r>>1)&3).  Read of block lq from row (..+lr): slot
// lq ^ ((lr>>1)&3) -> worst 2-way bank aliasing (free).
// ---------------------------------------------------------------------------
#define EPI_QKV       0  // z=0: Q2 plain; z=1: K2 swizzled; z=2: Vt swizzled-T
#define EPI_F32       3
#define EPI_SILU_BF16 4
#define EPI_SILU_F32  5
#define EPI_BIAS_F32  6

template <int EPI>
__global__ __launch_bounds__(256) void gemm_bt(
    const u16* __restrict__ A, int lda,
    const u16* __restrict__ W, int ldw,
    int M, int N, int K,
    float* __restrict__ outF, u16* __restrict__ outU,
    const float* __restrict__ bias,
    const u16* __restrict__ A2) {
  __shared__ u16 As[128 * 32];   // 8 KB
  __shared__ u16 Bs[128 * 32];   // 8 KB
  int tid = threadIdx.x;
  int l = tid & 63, w = tid >> 6;
  int wr = w >> 1, wc = w & 1, lr = l & 15, lq = l >> 4;
  int m0 = blockIdx.y * 128, n0 = blockIdx.x * 128;

  const u16* Ap = A;
  const u16* Wp = W;
  u16* outUp = outU;
  if constexpr (EPI == EPI_QKV) {
    int z = blockIdx.z;
    if (z) Ap = A2;                      // K,V read fusion
    Wp = W + (size_t)z * 1048576;        // wq / wk / wv
    outUp = outU + (size_t)z * 8388608;  // Q2 / K2 / Vt
  }

  f32x4 acc[4][4];
#pragma unroll
  for (int i = 0; i < 4; i++)
#pragma unroll
    for (int j = 0; j < 4; j++) acc[i][j] = zero4();

  auto stage = [&](const u16* src, int ld, int r0, int k0, u16* lds) {
#pragma unroll
    for (int j = 0; j < 2; ++j) {
      int seg = j * 256 + tid;               // 512 segs x 16B
      int row = seg >> 2, sp = seg & 3;
      const u16* g = src + (size_t)(r0 + row) * ld + k0 +
                     ((sp ^ ((row >> 1) & 3)) << 3);
      GLL16(g, lds + seg * 8);               // lane-contiguous LDS dest
    }
  };

  int nk = K >> 5;
  stage(Ap, lda, m0, 0, As);
  stage(Wp, ldw, n0, 0, Bs);
  for (int kt = 0; kt < nk; ++kt) {
    __syncthreads();                          // staging drained (vmcnt)
    bf16x8 af[4], bw[4];
    int slot = (lq ^ ((lr >> 1) & 3)) << 3;
#pragma unroll
    for (int mi = 0; mi < 4; mi++)
      af[mi] = *(const bf16x8*)&As[(wr * 64 + mi * 16 + lr) * 32 + slot];
#pragma unroll
    for (int ni = 0; ni < 4; ni++)
      bw[ni] = *(const bf16x8*)&Bs[(wc * 64 + ni * 16 + lr) * 32 + slot];
#pragma unroll
    for (int mi = 0; mi < 4; mi++)
#pragma unroll
      for (int ni = 0; ni < 4; ni++)
        acc[mi][ni] = __builtin_amdgcn_mfma_f32_16x16x32_bf16(af[mi], bw[ni],
                                                              acc[mi][ni], 0, 0, 0);
    __syncthreads();                          // reads done, safe to restage
    if (kt + 1 < nk) {
      stage(Ap, lda, m0, (kt + 1) << 5, As);
      stage(Wp, ldw, n0, (kt + 1) << 5, Bs);
    }
  }

#pragma unroll
  for (int mi = 0; mi < 4; mi++) {
#pragma unroll
    for (int ni = 0; ni < 4; ni++) {
      int col = n0 + wc * 64 + ni * 16 + lr;
#pragma unroll
      for (int r = 0; r < 4; r++) {
        int row = m0 + wr * 64 + mi * 16 + lq * 4 + r;
        float v = acc[mi][ni][r];
        if constexpr (EPI == EPI_QKV) {
          int b = row >> 10, t = row & 1023, h = col >> 6, d = col & 63;
          int z = blockIdx.z;
          if (z == 0) {                       // Q2: [bh][t][64] plain
            outUp[((size_t)(b * 16 + h) * 1024 + t) * 64 + d] = f2bf(v);
          } else if (z == 1) {                // K2: XOR-(t&7) swizzled rows
            size_t base = ((size_t)(b * 16 + h) * 1024 + t) * 64;
            outUp[base + (((d >> 3) ^ (t & 7)) << 3) + (d & 7)] = f2bf(v);
          } else {                            // Vt: [bh][d][t], XOR-(d&7) per 64-chunk
            size_t o = ((size_t)(b * 16 + h) * 64 + d) * 1024 + (t & ~63) +
                       ((((t >> 3) & 7) ^ (d & 7)) << 3) + (t & 7);
            outUp[o] = f2bf(v);
          }
        } else if constexpr (EPI == EPI_F32) {
          outF[(size_t)row * N + col] = v;
        } else if constexpr (EPI == EPI_SILU_BF16) {
          float z = v + bias[col];
          outUp[(size_t)row * N + col] = f2bf(z / (1.f + __expf(-z)));
        } else if constexpr (EPI == EPI_SILU_F32) {
          float z = v + bias[col];
          outF[(size_t)row * N + col] = z / (1.f + __expf(-z));
        } else {  // EPI_BIAS_F32
          outF[(size_t)row * N + col] = v + bias[col];
        }
      }
    }
  }
}

// ---------------------------------------------------------------------------
// Attention: two-pass recompute, plain bf16.
// Block 256 thr (4 waves), 128 q-rows (32/wave).  Grid (8, 16, 8).
// Q2 [bh][t][64] plain; K2 [bh][t][64] XOR-(t&7); Vt [bh][d][1024] XOR-(d&7).
// Pass 1: s1 = sum exp(s) (no max-subtract; scores ~N(0,1)).
// Pass 2: recompute s, a = exp(s)*inv_s1 masked, write masked, p = exp(a),
//         s2 += p, O += bf16(p) @ V; O * (1/s2) at end.
// Ps handoff (C-layout -> A-layout) is barrier-protected (__syncthreads).
// ---------------------------------------------------------------------------
__global__ __launch_bounds__(256) void attn_kernel(
    const u16* __restrict__ Q2, const u16* __restrict__ K2,
    const u16* __restrict__ Vt, const float* __restrict__ alphap,
    float* __restrict__ masked_out, u16* __restrict__ attn_out) {
  __shared__ __align__(16) u16 Ks[64 * 64];        // 8 KB
  __shared__ __align__(16) u16 Vs[64 * 64];        // 8 KB
  __shared__ __align__(16) u16 Ps[4][2][16 * 72];  // 18 KB

  int tid = threadIdx.x;
  int l = tid & 63, w = tid >> 6, lr = l & 15, lq = l >> 4;
  int q0 = blockIdx.x * 128;
  int h = blockIdx.y, b = blockIdx.z;
  int bh = b * 16 + h;
  const u16* Qb = Q2 + (size_t)bh * 1024 * 64;
  const u16* Kb = K2 + (size_t)bh * 1024 * 64;
  const u16* Vb = Vt + (size_t)bh * 64 * 1024;
  float alpha = alphap[0];
  int qw = q0 + w * 32;

  // Q fragments in registers: [sub 16-rows][k-chunk]
  bf16x8 qf[2][2];
#pragma unroll
  for (int s = 0; s < 2; s++)
#pragma unroll
    for (int kt = 0; kt < 2; kt++)
      qf[s][kt] = *(const bf16x8*)(Qb + (size_t)(qw + s * 16 + lr) * 64 + kt * 32 + lq * 8);

  float s1[2][4] = {{0.f, 0.f, 0.f, 0.f}, {0.f, 0.f, 0.f, 0.f}};

  // ---- pass 1 ----
  for (int kc = 0; kc < 16; ++kc) {
    __syncthreads();                            // prev Ks reads done
#pragma unroll
    for (int j = 0; j < 2; ++j) {
      int seg = j * 256 + tid;                  // 512 x 16B = 8 KB contiguous
      GLL16(Kb + (size_t)kc * 4096 + seg * 8, Ks + seg * 8);
    }
    __syncthreads();                            // staging drained
    f32x4 acc[2][4];
#pragma unroll
    for (int s = 0; s < 2; s++)
#pragma unroll
      for (int ni = 0; ni < 4; ni++) acc[s][ni] = zero4();
#pragma unroll
    for (int ni = 0; ni < 4; ++ni) {
      int t = ni * 16 + lr;
      bf16x8 k0 = *(const bf16x8*)&Ks[t * 64 + (((0 + lq) ^ (lr & 7)) << 3)];
      bf16x8 k1 = *(const bf16x8*)&Ks[t * 64 + (((4 + lq) ^ (lr & 7)) << 3)];
#pragma unroll
      for (int s = 0; s < 2; s++) {
        acc[s][ni] = __builtin_amdgcn_mfma_f32_16x16x32_bf16(qf[s][0], k0, acc[s][ni], 0, 0, 0);
        acc[s][ni] = __builtin_amdgcn_mfma_f32_16x16x32_bf16(qf[s][1], k1, acc[s][ni], 0, 0, 0);
      }
    }
#pragma unroll
    for (int s = 0; s < 2; s++)
#pragma unroll
      for (int ni = 0; ni < 4; ni++)
#pragma unroll
        for (int r = 0; r < 4; r++)
          s1[s][r] += __expf(acc[s][ni][r] * 0.125f);
  }
#pragma unroll
  for (int s = 0; s < 2; s++)
#pragma unroll
    for (int r = 0; r < 4; r++) {
      float v = s1[s][r];
      v += __shfl_xor(v, 1); v += __shfl_xor(v, 2);
      v += __shfl_xor(v, 4); v += __shfl_xor(v, 8);
      s1[s][r] = 1.0f / v;
    }

  // ---- pass 2 ----
  float s2[2][4] = {{0.f, 0.f, 0.f, 0.f}, {0.f, 0.f, 0.f, 0.f}};
  f32x4 oacc[2][4];
#pragma unroll
  for (int s = 0; s < 2; s++)
#pragma unroll
    for (int dg = 0; dg < 4; dg++) oacc[s][dg] = zero4();

  for (int kc = 0; kc < 16; ++kc) {
    __syncthreads();                            // prev Ks/Vs reads done
#pragma unroll
    for (int j = 0; j < 2; ++j) {
      int seg = j * 256 + tid;
      GLL16(Kb + (size_t)kc * 4096 + seg * 8, Ks + seg * 8);
    }
#pragma unroll
    for (int j = 0; j < 2; ++j) {
      int seg = j * 256 + tid;                  // row d = seg>>3, part = seg&7
      GLL16(Vb + (size_t)(seg >> 3) * 1024 + kc * 64 + (seg & 7) * 8, Vs + seg * 8);
    }
    __syncthreads();                            // staging drained

    f32x4 acc[2][4];
#pragma unroll
    for (int s = 0; s < 2; s++)
#pragma unroll
      for (int ni = 0; ni < 4; ni++) acc[s][ni] = zero4();
#pragma unroll
    for (int ni = 0; ni < 4; ++ni) {
      int t = ni * 16 + lr;
      bf16x8 k0 = *(const bf16x8*)&Ks[t * 64 + (((0 + lq) ^ (lr & 7)) << 3)];
      bf16x8 k1 = *(const bf16x8*)&Ks[t * 64 + (((4 + lq) ^ (lr & 7)) << 3)];
#pragma unroll
      for (int s = 0; s < 2; s++) {
        acc[s][ni] = __builtin_amdgcn_mfma_f32_16x16x32_bf16(qf[s][0], k0, acc[s][ni], 0, 0, 0);
        acc[s][ni] = __builtin_amdgcn_mfma_f32_16x16x32_bf16(qf[s][1], k1, acc[s][ni], 0, 0, 0);
      }
    }

#pragma unroll
    for (int s = 0; s < 2; s++) {
#pragma unroll
      for (int ni = 0; ni < 4; ni++) {
#pragma unroll
        for (int r = 0; r < 4; r++) {
          float e = __expf(acc[s][ni][r] * 0.125f);
          float a = e * s1[s][r];
          a = (a >= alpha) ? a : 0.0f;
          size_t row = (size_t)bh * 1024 + qw + s * 16 + lq * 4 + r;
          masked_out[row * 1024 + kc * 64 + ni * 16 + lr] = a;
          float p = __expf(a);
          s2[s][r] += p;
          Ps[w][s][(lq * 4 + r) * 72 + ni * 16 + lr] = f2bf(p);
        }
      }
    }
    __syncthreads();                            // Ps writes visible (bulletproof)

    bf16x8 pf[2][2];
#pragma unroll
    for (int s = 0; s < 2; s++)
#pragma unroll
      for (int kt = 0; kt < 2; kt++)
        pf[s][kt] = *(const bf16x8*)&Ps[w][s][lr * 72 + kt * 32 + lq * 8];
#pragma unroll
    for (int dg = 0; dg < 4; dg++) {
      int d = dg * 16 + lr;
      bf16x8 v0 = *(const bf16x8*)&Vs[d * 64 + (((0 + lq) ^ (lr & 7)) << 3)];
      bf16x8 v1 = *(const bf16x8*)&Vs[d * 64 + (((4 + lq) ^ (lr & 7)) << 3)];
#pragma unroll
      for (int s = 0; s < 2; s++) {
        oacc[s][dg] = __builtin_amdgcn_mfma_f32_16x16x32_bf16(pf[s][0], v0, oacc[s][dg], 0, 0, 0);
        oacc[s][dg] = __builtin_amdgcn_mfma_f32_16x16x32_bf16(pf[s][1], v1, oacc[s][dg], 0, 0, 0);
      }
    }
  }

#pragma unroll
  for (int s = 0; s < 2; s++)
#pragma unroll
    for (int r = 0; r < 4; r++) {
      float v = s2[s][r];
      v += __shfl_xor(v, 1); v += __shfl_xor(v, 2);
      v += __shfl_xor(v, 4); v += __shfl_xor(v, 8);
      s2[s][r] = 1.0f / v;
    }
#pragma unroll
  for (int s = 0; s < 2; s++)
#pragma unroll
    for (int dg = 0; dg < 4; dg++)
#pragma unroll
      for (int r = 0; r < 4; r++) {
        int q = qw + s * 16 + lq * 4 + r;
        attn_out[(size_t)(b * 1024 + q) * 1024 + h * 64 + dg * 16 + lr] =
            f2bf(oacc[s][dg][r] * s2[s][r]);
      }
}

// ---------------------------------------------------------------------------
// LayerNorm over D=1024
// ---------------------------------------------------------------------------
__global__ __launch_bounds__(256) void ln_kernel(
    const float* __restrict__ A, const float* __restrict__ Bv,
    const float* __restrict__ g, const float* __restrict__ beta,
    float* __restrict__ outF, u16* __restrict__ outB) {
  __shared__ float red[4];
  int row = blockIdx.x, t = threadIdx.x;
  const float* pa = A + (size_t)row * 1024;
  const float* pb = Bv + (size_t)row * 1024;
  float v[4];
  float s = 0.f;
#pragma unroll
  for (int i = 0; i < 4; i++) { int c = t + 256 * i; v[i] = pa[c] + pb[c]; s += v[i]; }
#pragma unroll
  for (int off = 1; off < 64; off <<= 1) s += __shfl_xor(s, off);
  if ((t & 63) == 0) red[t >> 6] = s;
  __syncthreads();
  s = red[0] + red[1] + red[2] + red[3];
  float mu = s * 0.0009765625f;
  float q = 0.f;
#pragma unroll
  for (int i = 0; i < 4; i++) { float d = v[i] - mu; q += d * d; }
  __syncthreads();
#pragma unroll
  for (int off = 1; off < 64; off <<= 1) q += __shfl_xor(q, off);
  if ((t & 63) == 0) red[t >> 6] = q;
  __syncthreads();
  q = red[0] + red[1] + red[2] + red[3];
  float rs = rsqrtf(q * 0.0009765625f + 1e-5f);
#pragma unroll
  for (int i = 0; i < 4; i++) {
    int c = t + 256 * i;
    float y = (v[i] - mu) * rs * g[c] + beta[c];
    if (outF) outF[(size_t)row * 1024 + c] = y;
    if (outB) outB[(size_t)row * 1024 + c] = f2bf(y);
  }
}

// ---------------------------------------------------------------------------
// Workspace (bytes), aliased by lifetime.  Total 182,452,224 B.
// ---------------------------------------------------------------------------
#define WS_BASEB   0            // [8192][1024] u16 = 16 MB (dead after QKV gemm)
#define WS_FUSB    16777216     // 16 MB (dead after QKV gemm)
#define WS_W       33554432     // 7 x [1024][1024] u16 = 14 MB
#define WS_QKV     48234496     // Q2 16MB | K2 16MB | Vt 16MB (dead after attn)
#define WS_ATTNO   98566144     // [8192][1024] u16 = 16 MB (dead after O gemm)
#define WS_O       115343360    // [8192][1024] f32 = 32 MB
#define WS_X       148897792    // [8192][1024] f32 = 32 MB
#define WS_XB      WS_BASEB                 // alias (baseb dead)
#define WS_H1      WS_ATTNO                 // alias (attno dead)
#define WS_FF      WS_QKV                   // f32 32 MB (Q2/K2 dead)
#define WS_YB      (WS_QKV + 33554432)      // alias Vt (dead)

extern "C" void kernel_launch(void* const* d_in, const int* in_sizes, int n_in,
                              void* d_out, int out_size, void* d_ws, size_t ws_size,
                              hipStream_t stream) {
  const float* base   = (const float*)d_in[0];
  const float* fusion = (const float*)d_in[1];
  const float* Wq     = (const float*)d_in[2];
  const float* Wk     = (const float*)d_in[3];
  const float* Wv     = (const float*)d_in[4];
  const float* Wo     = (const float*)d_in[5];
  const float* g1     = (const float*)d_in[6];
  const float* b1     = (const float*)d_in[7];
  const float* g2     = (const float*)d_in[8];
  const float* b2     = (const float*)d_in[9];
  const float* fc1w   = (const float*)d_in[10];
  const float* fc1b   = (const float*)d_in[11];
  const float* fc2w   = (const float*)d_in[12];
  const float* fc2b   = (const float*)d_in[13];
  const float* rw     = (const float*)d_in[14];
  const float* rb     = (const float*)d_in[15];
  const float* alphap = (const float*)d_in[16];

  char* ws = (char*)d_ws;
  u16* baseb  = (u16*)(ws + WS_BASEB);
  u16* fusb   = (u16*)(ws + WS_FUSB);
  u16* wall   = (u16*)(ws + WS_W);        // wq|wk|wv|wo|fc1|fc2|rw
  u16* Q2     = (u16*)(ws + WS_QKV);      // K2 = Q2+8388608, Vt = Q2+16777216 (elements)
  u16* attno  = (u16*)(ws + WS_ATTNO);
  float* obuf = (float*)(ws + WS_O);
  float* x    = (float*)(ws + WS_X);
  u16* xb     = (u16*)(ws + WS_XB);
  u16* h1     = (u16*)(ws + WS_H1);
  float* ff   = (float*)(ws + WS_FF);
  u16* yb     = (u16*)(ws + WS_YB);

  float* final_out  = (float*)d_out;
  float* masked_out = final_out + 8388608;

  // 1. pack
  pack_act<<<dim3(32768, 2), 256, 0, stream>>>(base, fusion, baseb, fusb);
  pack_w<<<dim3(4096, 7), 256, 0, stream>>>(Wq, Wk, Wv, Wo, fc1w, fc2w, rw, wall);

  dim3 gg(8, 64);

  // 2. QKV merged (z: 0=Q plain, 1=K swizzled, 2=Vt)
  gemm_bt<EPI_QKV><<<dim3(8, 64, 3), 256, 0, stream>>>(
      baseb, 1024, wall, 1024, 8192, 1024, 1024, nullptr, Q2, nullptr, fusb);

  // 3. attention
  attn_kernel<<<dim3(8, 16, 8), 256, 0, stream>>>(
      Q2, Q2 + 8388608, Q2 + 16777216, alphap, masked_out, attno);

  // 4. output proj + LN1
  gemm_bt<EPI_F32><<<gg, 256, 0, stream>>>(attno, 1024, wall + 3 * 1048576, 1024,
                                           8192, 1024, 1024, obuf, nullptr, nullptr, nullptr);
  ln_kernel<<<8192, 256, 0, stream>>>(base, obuf, g1, b1, x, xb);

  // 5. FFN + LN2
  gemm_bt<EPI_SILU_BF16><<<gg, 256, 0, stream>>>(xb, 1024, wall + 4 * 1048576, 1024,
                                                 8192, 1024, 1024, nullptr, h1, fc1b, nullptr);
  gemm_bt<EPI_SILU_F32><<<gg, 256, 0, stream>>>(h1, 1024, wall + 5 * 1048576, 1024,
                                                8192, 1024, 1024, ff, nullptr, fc2b, nullptr);
  ln_kernel<<<8192, 256, 0, stream>>>(x, ff, g2, b2, nullptr, yb);

  // 6. final projection
  gemm_bt<EPI_BIAS_F32><<<gg, 256, 0, stream>>>(yb, 1024, wall + 6 * 1048576, 1024,
                                                8192, 1024, 1024, final_out, nullptr, rb, nullptr);
}

// Round 5
// 1013.792 us; speedup vs baseline: 1.5778x; 1.0399x over previous
//
#include <hip/hip_runtime.h>

// ============================================================================
// CrossAttention fused pipeline, MI355X gfx950.  Round 5.
// - All K-loops single-ahead LDS double-buffered: sync -> stage(next) ->
//   compute(cur).  The vmcnt(0) barrier drain is covered by a full iteration
//   of MFMA instead of stalling cold (critical at 2 blocks/CU).
// - GEMM: BK=32 (m97/r4-proven inner structure), XOR LDS swizzle, dbuf.
// - Attention: two-pass recompute, dbuf K/V staging, wave-local Ps handoff
//   via s_waitcnt lgkmcnt(0) (r2-proven), 1 barrier per kc.
// - O-proj and fc2 outputs bf16 (saves 64 MB HBM traffic); LN reads bf16 Bv.
// ============================================================================

typedef unsigned short u16;
typedef __attribute__((ext_vector_type(8))) short  bf16x8;
typedef __attribute__((ext_vector_type(4))) float  f32x4;

#define GLL16(gp, lp) __builtin_amdgcn_global_load_lds(                     \
    (__attribute__((address_space(1))) const void*)(gp),                    \
    (__attribute__((address_space(3))) void*)(lp), 16, 0, 0)

__device__ __forceinline__ u16 f2bf(float x) {
  union { float f; unsigned u; } v; v.f = x;
  return (u16)((v.u + 0x7FFF + ((v.u >> 16) & 1)) >> 16);   // RNE
}
__device__ __forceinline__ float bf2f(u16 h) {
  union { unsigned u; float f; } v; v.u = ((unsigned)h) << 16;
  return v.f;
}
__device__ __forceinline__ f32x4 zero4() { f32x4 z = {0.f, 0.f, 0.f, 0.f}; return z; }

// ---------------------------------------------------------------------------
// Packing: activations (base,fusion) and 7 weights, fp32 -> bf16.
// ---------------------------------------------------------------------------
__global__ __launch_bounds__(256) void pack_act(const float* __restrict__ a,
                                                const float* __restrict__ b,
                                                u16* __restrict__ outa,
                                                u16* __restrict__ outb) {
  size_t i = (size_t)blockIdx.x * 256 + threadIdx.x;
  const float* in = blockIdx.y ? b : a;
  u16* out = blockIdx.y ? outb : outa;
  out[i] = f2bf(in[i]);
}

__global__ __launch_bounds__(256) void pack_w(
    const float* __restrict__ w0, const float* __restrict__ w1,
    const float* __restrict__ w2, const float* __restrict__ w3,
    const float* __restrict__ w4, const float* __restrict__ w5,
    const float* __restrict__ w6, u16* __restrict__ out) {
  size_t i = (size_t)blockIdx.x * 256 + threadIdx.x;
  const float* in;
  switch (blockIdx.y) {
    case 0: in = w0; break;  case 1: in = w1; break;
    case 2: in = w2; break;  case 3: in = w3; break;
    case 4: in = w4; break;  case 5: in = w5; break;
    default: in = w6; break;
  }
  out[(size_t)blockIdx.y * 1048576 + i] = f2bf(in[i]);
}

// ---------------------------------------------------------------------------
// GEMM: C[M,N] = A[M,K] @ W[N,K]^T, bf16, BK=32, double-buffered LDS.
// LDS row r holds 4x16B blocks; global block g stored at slot g ^ ((r>>1)&3).
// ---------------------------------------------------------------------------
#define EPI_QKV       0  // z=0: Q2 plain; z=1: K2 swizzled; z=2: Vt swizzled-T
#define EPI_BF16      1  // plain bf16 row-major
#define EPI_SILU_BF16 4  // silu(v+bias) -> bf16
#define EPI_BIAS_F32  6  // v+bias -> f32

template <int EPI>
__global__ __launch_bounds__(256) void gemm_bt(
    const u16* __restrict__ A, int lda,
    const u16* __restrict__ W, int ldw,
    int M, int N, int K,
    float* __restrict__ outF, u16* __restrict__ outU,
    const float* __restrict__ bias,
    const u16* __restrict__ A2) {
  __shared__ u16 As[2][128 * 32];   // 2 x 8 KB
  __shared__ u16 Bs[2][128 * 32];   // 2 x 8 KB
  int tid = threadIdx.x;
  int l = tid & 63, w = tid >> 6;
  int wr = w >> 1, wc = w & 1, lr = l & 15, lq = l >> 4;
  int m0 = blockIdx.y * 128, n0 = blockIdx.x * 128;

  const u16* Ap = A;
  const u16* Wp = W;
  u16* outUp = outU;
  if constexpr (EPI == EPI_QKV) {
    int z = blockIdx.z;
    if (z) Ap = A2;                      // K,V read fusion
    Wp = W + (size_t)z * 1048576;        // wq / wk / wv
    outUp = outU + (size_t)z * 8388608;  // Q2 / K2 / Vt
  }

  f32x4 acc[4][4];
#pragma unroll
  for (int i = 0; i < 4; i++)
#pragma unroll
    for (int j = 0; j < 4; j++) acc[i][j] = zero4();

  auto stage = [&](const u16* src, int ld, int r0, int k0, u16* lds) {
#pragma unroll
    for (int j = 0; j < 2; ++j) {
      int seg = j * 256 + tid;               // 512 segs x 16B
      int row = seg >> 2, sp = seg & 3;
      const u16* g = src + (size_t)(r0 + row) * ld + k0 +
                     ((sp ^ ((row >> 1) & 3)) << 3);
      GLL16(g, lds + seg * 8);               // lane-contiguous LDS dest
    }
  };

  int nk = K >> 5;
  stage(Ap, lda, m0, 0, As[0]);
  stage(Wp, ldw, n0, 0, Bs[0]);
  for (int kt = 0; kt < nk; ++kt) {
    __syncthreads();                          // drains stage(kt); prev reads done
    if (kt + 1 < nk) {                        // prefetch next tile (drained at
      stage(Ap, lda, m0, (kt + 1) << 5, As[(kt + 1) & 1]);   // NEXT sync, after
      stage(Wp, ldw, n0, (kt + 1) << 5, Bs[(kt + 1) & 1]);   // a full MFMA iter)
    }
    const u16* Ab = As[kt & 1];
    const u16* Bb = Bs[kt & 1];
    bf16x8 af[4], bw[4];
    int slot = (lq ^ ((lr >> 1) & 3)) << 3;
#pragma unroll
    for (int mi = 0; mi < 4; mi++)
      af[mi] = *(const bf16x8*)&Ab[(wr * 64 + mi * 16 + lr) * 32 + slot];
#pragma unroll
    for (int ni = 0; ni < 4; ni++)
      bw[ni] = *(const bf16x8*)&Bb[(wc * 64 + ni * 16 + lr) * 32 + slot];
#pragma unroll
    for (int mi = 0; mi < 4; mi++)
#pragma unroll
      for (int ni = 0; ni < 4; ni++)
        acc[mi][ni] = __builtin_amdgcn_mfma_f32_16x16x32_bf16(af[mi], bw[ni],
                                                              acc[mi][ni], 0, 0, 0);
  }

#pragma unroll
  for (int mi = 0; mi < 4; mi++) {
#pragma unroll
    for (int ni = 0; ni < 4; ni++) {
      int col = n0 + wc * 64 + ni * 16 + lr;
#pragma unroll
      for (int r = 0; r < 4; r++) {
        int row = m0 + wr * 64 + mi * 16 + lq * 4 + r;
        float v = acc[mi][ni][r];
        if constexpr (EPI == EPI_QKV) {
          int b = row >> 10, t = row & 1023, h = col >> 6, d = col & 63;
          int z = blockIdx.z;
          if (z == 0) {                       // Q2: [bh][t][64] plain
            outUp[((size_t)(b * 16 + h) * 1024 + t) * 64 + d] = f2bf(v);
          } else if (z == 1) {                // K2: XOR-(t&7) swizzled rows
            size_t base = ((size_t)(b * 16 + h) * 1024 + t) * 64;
            outUp[base + (((d >> 3) ^ (t & 7)) << 3) + (d & 7)] = f2bf(v);
          } else {                            // Vt: [bh][d][t], XOR-(d&7) per 64-chunk
            size_t o = ((size_t)(b * 16 + h) * 64 + d) * 1024 + (t & ~63) +
                       ((((t >> 3) & 7) ^ (d & 7)) << 3) + (t & 7);
            outUp[o] = f2bf(v);
          }
        } else if constexpr (EPI == EPI_BF16) {
          outUp[(size_t)row * N + col] = f2bf(v);
        } else if constexpr (EPI == EPI_SILU_BF16) {
          float z = v + bias[col];
          outUp[(size_t)row * N + col] = f2bf(z / (1.f + __expf(-z)));
        } else {  // EPI_BIAS_F32
          outF[(size_t)row * N + col] = v + bias[col];
        }
      }
    }
  }
}

// ---------------------------------------------------------------------------
// Attention: two-pass recompute, plain bf16, dbuf K/V staging.
// Block 256 thr (4 waves), 128 q-rows (32/wave).  Grid (8, 16, 8).
// Q2 [bh][t][64] plain; K2 [bh][t][64] XOR-(t&7); Vt [bh][d][1024] XOR-(d&7).
// ---------------------------------------------------------------------------
__global__ __launch_bounds__(256) void attn_kernel(
    const u16* __restrict__ Q2, const u16* __restrict__ K2,
    const u16* __restrict__ Vt, const float* __restrict__ alphap,
    float* __restrict__ masked_out, u16* __restrict__ attn_out) {
  __shared__ __align__(16) u16 Ks[2][4096];        // 16 KB
  __shared__ __align__(16) u16 Vs[2][4096];        // 16 KB
  __shared__ __align__(16) u16 Ps[4][2][16 * 72];  // 18 KB

  int tid = threadIdx.x;
  int l = tid & 63, w = tid >> 6, lr = l & 15, lq = l >> 4;
  int q0 = blockIdx.x * 128;
  int h = blockIdx.y, b = blockIdx.z;
  int bh = b * 16 + h;
  const u16* Qb = Q2 + (size_t)bh * 1024 * 64;
  const u16* Kb = K2 + (size_t)bh * 1024 * 64;
  const u16* Vb = Vt + (size_t)bh * 64 * 1024;
  float alpha = alphap[0];
  int qw = q0 + w * 32;

  auto stageK = [&](int kc, u16* dst) {
#pragma unroll
    for (int j = 0; j < 2; ++j) {
      int seg = j * 256 + tid;
      GLL16(Kb + (size_t)kc * 4096 + seg * 8, dst + seg * 8);
    }
  };
  auto stageV = [&](int kc, u16* dst) {
#pragma unroll
    for (int j = 0; j < 2; ++j) {
      int seg = j * 256 + tid;                  // row d = seg>>3, part = seg&7
      GLL16(Vb + (size_t)(seg >> 3) * 1024 + kc * 64 + (seg & 7) * 8, dst + seg * 8);
    }
  };

  // Q fragments in registers: [sub 16-rows][k-chunk]
  bf16x8 qf[2][2];
#pragma unroll
  for (int s = 0; s < 2; s++)
#pragma unroll
    for (int kt = 0; kt < 2; kt++)
      qf[s][kt] = *(const bf16x8*)(Qb + (size_t)(qw + s * 16 + lr) * 64 + kt * 32 + lq * 8);

  float s1[2][4] = {{0.f, 0.f, 0.f, 0.f}, {0.f, 0.f, 0.f, 0.f}};

  // ---- pass 1 ----
  stageK(0, Ks[0]);
  for (int kc = 0; kc < 16; ++kc) {
    __syncthreads();                            // drains stage(kc); prev reads done
    if (kc + 1 < 16) stageK(kc + 1, Ks[(kc + 1) & 1]);
    const u16* Kc = Ks[kc & 1];
    f32x4 acc[2][4];
#pragma unroll
    for (int s = 0; s < 2; s++)
#pragma unroll
      for (int ni = 0; ni < 4; ni++) acc[s][ni] = zero4();
#pragma unroll
    for (int ni = 0; ni < 4; ++ni) {
      int t = ni * 16 + lr;
      bf16x8 k0 = *(const bf16x8*)&Kc[t * 64 + (((0 + lq) ^ (lr & 7)) << 3)];
      bf16x8 k1 = *(const bf16x8*)&Kc[t * 64 + (((4 + lq) ^ (lr & 7)) << 3)];
#pragma unroll
      for (int s = 0; s < 2; s++) {
        acc[s][ni] = __builtin_amdgcn_mfma_f32_16x16x32_bf16(qf[s][0], k0, acc[s][ni], 0, 0, 0);
        acc[s][ni] = __builtin_amdgcn_mfma_f32_16x16x32_bf16(qf[s][1], k1, acc[s][ni], 0, 0, 0);
      }
    }
#pragma unroll
    for (int s = 0; s < 2; s++)
#pragma unroll
      for (int ni = 0; ni < 4; ni++)
#pragma unroll
        for (int r = 0; r < 4; r++)
          s1[s][r] += __expf(acc[s][ni][r] * 0.125f);
  }
#pragma unroll
  for (int s = 0; s < 2; s++)
#pragma unroll
    for (int r = 0; r < 4; r++) {
      float v = s1[s][r];
      v += __shfl_xor(v, 1); v += __shfl_xor(v, 2);
      v += __shfl_xor(v, 4); v += __shfl_xor(v, 8);
      s1[s][r] = 1.0f / v;
    }

  // ---- pass 2 ----
  float s2[2][4] = {{0.f, 0.f, 0.f, 0.f}, {0.f, 0.f, 0.f, 0.f}};
  f32x4 oacc[2][4];
#pragma unroll
  for (int s = 0; s < 2; s++)
#pragma unroll
    for (int dg = 0; dg < 4; dg++) oacc[s][dg] = zero4();

  stageK(0, Ks[0]);                             // Ks[0] reads drained at kc=15 sync
  stageV(0, Vs[0]);
  for (int kc = 0; kc < 16; ++kc) {
    __syncthreads();                            // drains stage(kc); prev reads done
    if (kc + 1 < 16) {
      stageK(kc + 1, Ks[(kc + 1) & 1]);
      stageV(kc + 1, Vs[(kc + 1) & 1]);
    }
    const u16* Kc = Ks[kc & 1];
    const u16* Vc = Vs[kc & 1];

    f32x4 acc[2][4];
#pragma unroll
    for (int s = 0; s < 2; s++)
#pragma unroll
      for (int ni = 0; ni < 4; ni++) acc[s][ni] = zero4();
#pragma unroll
    for (int ni = 0; ni < 4; ++ni) {
      int t = ni * 16 + lr;
      bf16x8 k0 = *(const bf16x8*)&Kc[t * 64 + (((0 + lq) ^ (lr & 7)) << 3)];
      bf16x8 k1 = *(const bf16x8*)&Kc[t * 64 + (((4 + lq) ^ (lr & 7)) << 3)];
#pragma unroll
      for (int s = 0; s < 2; s++) {
        acc[s][ni] = __builtin_amdgcn_mfma_f32_16x16x32_bf16(qf[s][0], k0, acc[s][ni], 0, 0, 0);
        acc[s][ni] = __builtin_amdgcn_mfma_f32_16x16x32_bf16(qf[s][1], k1, acc[s][ni], 0, 0, 0);
      }
    }

#pragma unroll
    for (int s = 0; s < 2; s++) {
#pragma unroll
      for (int ni = 0; ni < 4; ni++) {
#pragma unroll
        for (int r = 0; r < 4; r++) {
          float e = __expf(acc[s][ni][r] * 0.125f);
          float a = e * s1[s][r];
          a = (a >= alpha) ? a : 0.0f;
          size_t row = (size_t)bh * 1024 + qw + s * 16 + lq * 4 + r;
          masked_out[row * 1024 + kc * 64 + ni * 16 + lr] = a;
          float p = __expf(a);
          s2[s][r] += p;
          Ps[w][s][(lq * 4 + r) * 72 + ni * 16 + lr] = f2bf(p);
        }
      }
    }
    // wave-local Ps handoff: Ps[w] is written and read only by wave w.
    // r2-proven: all outstanding DS ops complete before the reads below.
    asm volatile("s_waitcnt lgkmcnt(0)" ::: "memory");

    bf16x8 pf[2][2];
#pragma unroll
    for (int s = 0; s < 2; s++)
#pragma unroll
      for (int kt = 0; kt < 2; kt++)
        pf[s][kt] = *(const bf16x8*)&Ps[w][s][lr * 72 + kt * 32 + lq * 8];
#pragma unroll
    for (int dg = 0; dg < 4; dg++) {
      int d = dg * 16 + lr;
      bf16x8 v0 = *(const bf16x8*)&Vc[d * 64 + (((0 + lq) ^ (lr & 7)) << 3)];
      bf16x8 v1 = *(const bf16x8*)&Vc[d * 64 + (((4 + lq) ^ (lr & 7)) << 3)];
#pragma unroll
      for (int s = 0; s < 2; s++) {
        oacc[s][dg] = __builtin_amdgcn_mfma_f32_16x16x32_bf16(pf[s][0], v0, oacc[s][dg], 0, 0, 0);
        oacc[s][dg] = __builtin_amdgcn_mfma_f32_16x16x32_bf16(pf[s][1], v1, oacc[s][dg], 0, 0, 0);
      }
    }
  }

#pragma unroll
  for (int s = 0; s < 2; s++)
#pragma unroll
    for (int r = 0; r < 4; r++) {
      float v = s2[s][r];
      v += __shfl_xor(v, 1); v += __shfl_xor(v, 2);
      v += __shfl_xor(v, 4); v += __shfl_xor(v, 8);
      s2[s][r] = 1.0f / v;
    }
#pragma unroll
  for (int s = 0; s < 2; s++)
#pragma unroll
    for (int dg = 0; dg < 4; dg++)
#pragma unroll
      for (int r = 0; r < 4; r++) {
        int q = qw + s * 16 + lq * 4 + r;
        attn_out[(size_t)(b * 1024 + q) * 1024 + h * 64 + dg * 16 + lr] =
            f2bf(oacc[s][dg][r] * s2[s][r]);
      }
}

// ---------------------------------------------------------------------------
// LayerNorm over D=1024: y = (A + bf2f(Bv) - mu)*rsqrt(var+eps)*g + beta
// ---------------------------------------------------------------------------
__global__ __launch_bounds__(256) void ln_kernel(
    const float* __restrict__ A, const u16* __restrict__ Bv,
    const float* __restrict__ g, const float* __restrict__ beta,
    float* __restrict__ outF, u16* __restrict__ outB) {
  __shared__ float red[4];
  int row = blockIdx.x, t = threadIdx.x;
  const float* pa = A + (size_t)row * 1024;
  const u16* pb = Bv + (size_t)row * 1024;
  float v[4];
  float s = 0.f;
#pragma unroll
  for (int i = 0; i < 4; i++) {
    int c = t + 256 * i;
    v[i] = pa[c] + bf2f(pb[c]);
    s += v[i];
  }
#pragma unroll
  for (int off = 1; off < 64; off <<= 1) s += __shfl_xor(s, off);
  if ((t & 63) == 0) red[t >> 6] = s;
  __syncthreads();
  s = red[0] + red[1] + red[2] + red[3];
  float mu = s * 0.0009765625f;
  float q = 0.f;
#pragma unroll
  for (int i = 0; i < 4; i++) { float d = v[i] - mu; q += d * d; }
  __syncthreads();
#pragma unroll
  for (int off = 1; off < 64; off <<= 1) q += __shfl_xor(q, off);
  if ((t & 63) == 0) red[t >> 6] = q;
  __syncthreads();
  q = red[0] + red[1] + red[2] + red[3];
  float rs = rsqrtf(q * 0.0009765625f + 1e-5f);
#pragma unroll
  for (int i = 0; i < 4; i++) {
    int c = t + 256 * i;
    float y = (v[i] - mu) * rs * g[c] + beta[c];
    if (outF) outF[(size_t)row * 1024 + c] = y;
    if (outB) outB[(size_t)row * 1024 + c] = f2bf(y);
  }
}

// ---------------------------------------------------------------------------
// Workspace (bytes), aliased by lifetime.  Total 148,897,792 + 33 MB.
// ---------------------------------------------------------------------------
#define WS_BASEB   0            // [8192][1024] u16 = 16 MB (dead after QKV gemm)
#define WS_FUSB    16777216     // 16 MB (dead after QKV gemm)
#define WS_W       33554432     // 7 x [1024][1024] u16 = 14 MB
#define WS_QKV     48234496     // Q2 16MB | K2 16MB | Vt 16MB (dead after attn)
#define WS_ATTNO   98566144     // [8192][1024] u16 = 16 MB (dead after O gemm)
#define WS_X       115343360    // [8192][1024] f32 = 32 MB (ends 148897792)
#define WS_OB      WS_FUSB                  // [8192][1024] u16 (fusb dead)
#define WS_XB      WS_BASEB                 // [8192][1024] u16 (baseb dead)
#define WS_H1      WS_ATTNO                 // alias (attno dead)
#define WS_FFB     WS_QKV                   // alias Q2 (dead after attn)
#define WS_YB      (WS_QKV + 16777216)      // alias K2 (dead)

extern "C" void kernel_launch(void* const* d_in, const int* in_sizes, int n_in,
                              void* d_out, int out_size, void* d_ws, size_t ws_size,
                              hipStream_t stream) {
  const float* base   = (const float*)d_in[0];
  const float* fusion = (const float*)d_in[1];
  const float* Wq     = (const float*)d_in[2];
  const float* Wk     = (const float*)d_in[3];
  const float* Wv     = (const float*)d_in[4];
  const float* Wo     = (const float*)d_in[5];
  const float* g1     = (const float*)d_in[6];
  const float* b1     = (const float*)d_in[7];
  const float* g2     = (const float*)d_in[8];
  const float* b2     = (const float*)d_in[9];
  const float* fc1w   = (const float*)d_in[10];
  const float* fc1b   = (const float*)d_in[11];
  const float* fc2w   = (const float*)d_in[12];
  const float* fc2b   = (const float*)d_in[13];
  const float* rw     = (const float*)d_in[14];
  const float* rb     = (const float*)d_in[15];
  const float* alphap = (const float*)d_in[16];

  char* ws = (char*)d_ws;
  u16* baseb  = (u16*)(ws + WS_BASEB);
  u16* fusb   = (u16*)(ws + WS_FUSB);
  u16* wall   = (u16*)(ws + WS_W);        // wq|wk|wv|wo|fc1|fc2|rw
  u16* Q2     = (u16*)(ws + WS_QKV);      // K2 = Q2+8388608, Vt = Q2+16777216 (elems)
  u16* attno  = (u16*)(ws + WS_ATTNO);
  u16* obufb  = (u16*)(ws + WS_OB);
  float* x    = (float*)(ws + WS_X);
  u16* xb     = (u16*)(ws + WS_XB);
  u16* h1     = (u16*)(ws + WS_H1);
  u16* ffb    = (u16*)(ws + WS_FFB);
  u16* yb     = (u16*)(ws + WS_YB);

  float* final_out  = (float*)d_out;
  float* masked_out = final_out + 8388608;

  // 1. pack
  pack_act<<<dim3(32768, 2), 256, 0, stream>>>(base, fusion, baseb, fusb);
  pack_w<<<dim3(4096, 7), 256, 0, stream>>>(Wq, Wk, Wv, Wo, fc1w, fc2w, rw, wall);

  dim3 gg(8, 64);

  // 2. QKV merged (z: 0=Q plain, 1=K swizzled, 2=Vt)
  gemm_bt<EPI_QKV><<<dim3(8, 64, 3), 256, 0, stream>>>(
      baseb, 1024, wall, 1024, 8192, 1024, 1024, nullptr, Q2, nullptr, fusb);

  // 3. attention
  attn_kernel<<<dim3(8, 16, 8), 256, 0, stream>>>(
      Q2, Q2 + 8388608, Q2 + 16777216, alphap, masked_out, attno);

  // 4. output proj (bf16 out) + LN1
  gemm_bt<EPI_BF16><<<gg, 256, 0, stream>>>(attno, 1024, wall + 3 * 1048576, 1024,
                                            8192, 1024, 1024, nullptr, obufb, nullptr, nullptr);
  ln_kernel<<<8192, 256, 0, stream>>>(base, obufb, g1, b1, x, xb);

  // 5. FFN + LN2
  gemm_bt<EPI_SILU_BF16><<<gg, 256, 0, stream>>>(xb, 1024, wall + 4 * 1048576, 1024,
                                                 8192, 1024, 1024, nullptr, h1, fc1b, nullptr);
  gemm_bt<EPI_SILU_BF16><<<gg, 256, 0, stream>>>(h1, 1024, wall + 5 * 1048576, 1024,
                                                 8192, 1024, 1024, nullptr, ffb, fc2b, nullptr);
  ln_kernel<<<8192, 256, 0, stream>>>(x, ffb, g2, b2, nullptr, yb);

  // 6. final projection
  gemm_bt<EPI_BIAS_F32><<<gg, 256, 0, stream>>>(yb, 1024, wall + 6 * 1048576, 1024,
                                                8192, 1024, 1024, final_out, nullptr, rb, nullptr);
}